// Round 6
// baseline (324.868 us; speedup 1.0000x reference)
//
#include <hip/hip_runtime.h>

#define DEVI __device__ __forceinline__

typedef __attribute__((ext_vector_type(4))) float f32x4;
typedef __attribute__((ext_vector_type(8))) short bf16x8;
typedef __attribute__((ext_vector_type(4))) unsigned int u32x4;

typedef __attribute__((address_space(3))) unsigned int lds_u32_t;
typedef __attribute__((address_space(1))) unsigned int glb_u32_t;

// ---------- constants ----------
constexpr int KTOT  = 66048;          // 65536 main + 256 inp1-linear + 256 inp2-linear
// workspace offsets (bytes)
constexpr size_t OFF_WPT  = 0;                      // Wp_t bf16 [256][66048]  = 33,816,576
constexpr size_t OFF_W2BT = 33816576;               // W2^T bf16 [256][256]    = 131,072
constexpr size_t OFF_B1P  = OFF_W2BT + 131072;      // b1 + W1[66048,:] f32    = 1,024
constexpr size_t OFF_HF   = OFF_B1P + 1024;         // h fp32 [4096][256]      = 4,194,304
constexpr size_t OFF_HB   = OFF_HF + 4194304;       // h bf16 [4096][256]      = 2,097,152

// ---------- bf16 helpers (RNE) ----------
DEVI unsigned int f2bf_u(float x) {
  unsigned int u = __float_as_uint(x);
  return (u + 0x7FFFu + ((u >> 16) & 1u)) >> 16;
}
DEVI unsigned int pack2(float a, float b) { return f2bf_u(a) | (f2bf_u(b) << 16); }

// =====================================================================
// K0: repack W1 (f32 [66049][256]) -> Wp_t (bf16 [256 n][66048 k'])
// =====================================================================
__global__ __launch_bounds__(256) void k_repack(const float* __restrict__ W1,
                                                unsigned short* __restrict__ wpt) {
  __shared__ float tile[64][65];
  int kt = blockIdx.x, nt = blockIdx.y, t = threadIdx.x;
  {
    int r = t >> 2, c4 = (t & 3) * 16;
    int kp = kt * 64 + r;
    int src;
    if (kp < 65536)      src = (kp >> 8) * 257 + (kp & 255);
    else if (kp < 65792) src = (kp - 65536) * 257 + 256;
    else                 src = kp;
    const float* rp = W1 + (size_t)src * 256 + nt * 64 + c4;
#pragma unroll
    for (int q = 0; q < 4; ++q) {
      f32x4 x = *(const f32x4*)(rp + q * 4);
#pragma unroll
      for (int e = 0; e < 4; ++e) tile[r][c4 + q * 4 + e] = x[e];
    }
  }
  __syncthreads();
  {
    int nl = t >> 2, kk = (t & 3) * 16;
    int n = nt * 64 + nl;
    u32x4 lo, hi;
#pragma unroll
    for (int m = 0; m < 4; ++m)
      lo[m] = pack2(tile[kk + 2 * m][nl], tile[kk + 2 * m + 1][nl]);
#pragma unroll
    for (int m = 0; m < 4; ++m)
      hi[m] = pack2(tile[kk + 8 + 2 * m][nl], tile[kk + 9 + 2 * m][nl]);
    unsigned short* dst = wpt + (size_t)n * KTOT + kt * 64 + kk;
    *(u32x4*)dst = lo;
    *(u32x4*)(dst + 8) = hi;
  }
}

// =====================================================================
// K1: zero h_f32; W2 -> W2^T bf16; b1p = b1 + W1[66048,:]
// =====================================================================
__global__ __launch_bounds__(256) void k_misc(const float* __restrict__ W1,
                                              const float* __restrict__ b1,
                                              const float* __restrict__ W2,
                                              float* __restrict__ hf,
                                              unsigned short* __restrict__ w2bt,
                                              float* __restrict__ b1p) {
  int idx = blockIdx.x * 256 + threadIdx.x;
  hf[idx] = 0.f;
  if (idx < 65536) {
    int n2 = idx >> 8, n = idx & 255;
    w2bt[idx] = (unsigned short)f2bf_u(W2[n * 256 + n2]);
  }
  if (idx < 256) b1p[idx] = b1[idx] + W1[(size_t)66048 * 256 + idx];
}

// =====================================================================
// K2: main bilinear GEMM. BM=128, BN=256, BK=32, 512 thr (8 waves 2x4,
//     wave tile 64x64), dbuf LDS 48K -> 2 blocks/CU (16 waves).
//     grid 512 = 16 i-chunks x 32 batch-blocks, XCD-pinned chunks.
//     LDS swizzle for 64B rows: unit u ^ ((row>>1)&3) (reads/writes/stage src).
// =====================================================================
__global__ __launch_bounds__(512, 4) void k_main(const float* __restrict__ inp1,
                                                 const float* __restrict__ inp2,
                                                 const unsigned short* __restrict__ wpt,
                                                 float* __restrict__ hf) {
  __shared__ char smem[49152];   // 2 x (A 8K @+0, W 16K @+8192), stride 24576

  int lin = blockIdx.x;                           // 0..511
  int xcd = lin & 7, slot = lin >> 3;             // slot 0..63
  int c = xcd + ((slot >> 5) << 3);               // i-chunk 0..15 (XCD-pinned)
  int bblk = slot & 31;
  int b0 = bblk * 128;
  int i0 = c * 16;

  int t = threadIdx.x;
  int lane = t & 63, w = t >> 6;
  int wr = w >> 2, wc = w & 3;                    // 2 x 4 waves, tile 64 x 64
  int r16 = lane & 15, kun = lane >> 4;

  int row_a = t >> 2;                             // builder row 0..127
  int u_a = t & 3;                                // builder unit 0..3
  int a_waddr = row_a * 64 + ((u_a ^ ((row_a >> 1) & 3)) << 4);

  const float* inp1_row = inp1 + (size_t)(b0 + row_a) * 256;
  const float* inp2_row = inp2 + (size_t)(b0 + row_a) * 256;

  char* A0 = smem;             char* W0 = smem + 8192;
  char* A1 = smem + 24576;     char* W1b = smem + 24576 + 8192;

  float v[16];                                    // thread's 16 inp2 values per js64-window
  auto loadv = [&](int js) {
    const float* p = inp2_row + js * 64 + u_a * 8;
#pragma unroll
    for (int jw = 0; jw < 2; ++jw) {
      f32x4 x0 = *(const f32x4*)(p + jw * 32);
      f32x4 x1 = *(const f32x4*)(p + jw * 32 + 4);
#pragma unroll
      for (int e = 0; e < 4; ++e) { v[jw * 8 + e] = x0[e]; v[jw * 8 + 4 + e] = x1[e]; }
    }
  };

  auto build_main = [&](char* A, int ii, int jw) {
    float s = inp1_row[i0 + ii];
    u32x4 pk;
#pragma unroll
    for (int m = 0; m < 4; ++m)
      pk[m] = pack2(v[jw * 8 + 2 * m] * s, v[jw * 8 + 2 * m + 1] * s);
    *(u32x4*)(A + a_waddr) = pk;
  };

  auto build_tail = [&](char* A) {
    int koff = c * 32 + u_a * 8;                  // 0..511
    const float* src = (koff < 256) ? (inp1_row + koff) : (inp2_row + (koff - 256));
    f32x4 x0 = *(const f32x4*)src;
    f32x4 x1 = *(const f32x4*)(src + 4);
    u32x4 pk;
    pk[0] = pack2(x0[0], x0[1]);
    pk[1] = pack2(x0[2], x0[3]);
    pk[2] = pack2(x1[0], x1[1]);
    pk[3] = pack2(x1[2], x1[3]);
    *(u32x4*)(A + a_waddr) = pk;
  };

  auto stage = [&](char* W, int k0) {
#pragma unroll
    for (int sI = 0; sI < 2; ++sI) {
      int g = w * 128 + sI * 64 + lane;           // 0..1023 : n = g>>2, unit u = g&3
      int n = g >> 2, u = g & 3;
      size_t gb = (size_t)n * (KTOT * 2) +
                  (size_t)((k0 + ((u ^ ((n >> 1) & 3)) << 3)) * 2);
      __builtin_amdgcn_global_load_lds((const glb_u32_t*)((const char*)wpt + gb),
                                       (lds_u32_t*)(W + g * 16), 16, 0, 0);
    }
  };

  f32x4 acc[4][4] = {};

  auto mfma_step = [&](const char* A, const char* W) {
    bf16x8 a[4], b[4];
#pragma unroll
    for (int rg = 0; rg < 4; ++rg) {
      int row = wr * 64 + rg * 16 + r16;
      a[rg] = *(const bf16x8*)(A + row * 64 + ((kun ^ ((row >> 1) & 3)) << 4));
    }
#pragma unroll
    for (int cg = 0; cg < 4; ++cg) {
      int n = wc * 64 + cg * 16 + r16;
      b[cg] = *(const bf16x8*)(W + n * 64 + ((kun ^ ((n >> 1) & 3)) << 4));
    }
#pragma unroll
    for (int rg = 0; rg < 4; ++rg)
#pragma unroll
      for (int cg = 0; cg < 4; ++cg)
        acc[rg][cg] = __builtin_amdgcn_mfma_f32_16x16x32_bf16(a[rg], b[cg], acc[rg][cg], 0, 0, 0);
  };

  // step s in [0,129): s<128: js = s>>5, ii = (s>>1)&15, jw = s&1; s=128: tail (k'=65536+c*32)
  // prologue: stage step 0 into buf 0
  loadv(0);
  stage(W0, i0 * 256);
  build_main(A0, 0, 0);
  __syncthreads();

  for (int s2 = 0; s2 < 64; ++s2) {
    {   // compute s = 2*s2 (buf0), prefetch sn = 2*s2+1 (buf1); sn odd -> jw=1, js/ii current
      int sn = 2 * s2 + 1;
      int js = sn >> 5, ii = (sn >> 1) & 15;
      stage(W1b, (i0 + ii) * 256 + js * 64 + 32);
      build_main(A1, ii, 1);
      mfma_step(A0, W0);
      __syncthreads();
    }
    {   // compute s = 2*s2+1 (buf1), prefetch sn = 2*s2+2 (buf0)
      int sn = 2 * s2 + 2;
      if (sn < 128) {
        int js = sn >> 5, ii = (sn >> 1) & 15;
        stage(W0, (i0 + ii) * 256 + js * 64);
        if ((sn & 31) == 0) loadv(js);
        build_main(A0, ii, 0);
      } else {
        stage(W0, 65536 + c * 32);
        build_tail(A0);
      }
      mfma_step(A1, W1b);
      __syncthreads();
    }
  }
  mfma_step(A0, W0);                              // tail step s=128

  // epilogue: fp32 atomic accumulate (split-K over 16 chunks)
#pragma unroll
  for (int rg = 0; rg < 4; ++rg)
#pragma unroll
    for (int cg = 0; cg < 4; ++cg) {
      int n = wc * 64 + cg * 16 + r16;
      int brow = b0 + wr * 64 + rg * 16 + kun * 4;
#pragma unroll
      for (int r = 0; r < 4; ++r)
        atomicAdd(hf + (size_t)(brow + r) * 256 + n, acc[rg][cg][r]);
    }
}

// =====================================================================
// K3: h = relu(hf + b1p) -> bf16
// =====================================================================
__global__ __launch_bounds__(256) void k_finalize(const float* __restrict__ hf,
                                                  const float* __restrict__ b1p,
                                                  unsigned short* __restrict__ hb) {
  int idx = blockIdx.x * 256 + threadIdx.x;
  float v = hf[idx] + b1p[idx & 255];
  hb[idx] = (unsigned short)f2bf_u(v > 0.f ? v : 0.f);
}

// =====================================================================
// K4: out = relu(h @ W2 + b2)
// =====================================================================
__global__ __launch_bounds__(256) void k_gemm2(const unsigned short* __restrict__ hb,
                                               const unsigned short* __restrict__ w2bt,
                                               const float* __restrict__ b2,
                                               float* __restrict__ out) {
  int b0 = blockIdx.x * 128, n0 = blockIdx.y * 128;
  int t = threadIdx.x, lane = t & 63, w = t >> 6;
  int wr = w >> 1, wc = w & 1;
  int r16 = lane & 15, k8 = (lane >> 4) * 8;
  f32x4 acc[4][4] = {};
  for (int ks = 0; ks < 8; ++ks) {
    int k = ks * 32 + k8;
    bf16x8 a[4], bb[4];
#pragma unroll
    for (int rg = 0; rg < 4; ++rg) {
      int b_ = b0 + wr * 64 + rg * 16 + r16;
      a[rg] = *(const bf16x8*)(hb + (size_t)b_ * 256 + k);
    }
#pragma unroll
    for (int cg = 0; cg < 4; ++cg) {
      int n2 = n0 + wc * 64 + cg * 16 + r16;
      bb[cg] = *(const bf16x8*)(w2bt + (size_t)n2 * 256 + k);
    }
#pragma unroll
    for (int rg = 0; rg < 4; ++rg)
#pragma unroll
      for (int cg = 0; cg < 4; ++cg)
        acc[rg][cg] = __builtin_amdgcn_mfma_f32_16x16x32_bf16(a[rg], bb[cg], acc[rg][cg], 0, 0, 0);
  }
#pragma unroll
  for (int rg = 0; rg < 4; ++rg)
#pragma unroll
    for (int cg = 0; cg < 4; ++cg) {
      int n2 = n0 + wc * 64 + cg * 16 + r16;
      float bias = b2[n2];
      int brow = b0 + wr * 64 + rg * 16 + (lane >> 4) * 4;
#pragma unroll
      for (int r = 0; r < 4; ++r) {
        float val = acc[rg][cg][r] + bias;
        out[(size_t)(brow + r) * 256 + n2] = val > 0.f ? val : 0.f;
      }
    }
}

// =====================================================================
extern "C" void kernel_launch(void* const* d_in, const int* in_sizes, int n_in,
                              void* d_out, int out_size, void* d_ws, size_t ws_size,
                              hipStream_t stream) {
  const float* inp1 = (const float*)d_in[0];
  const float* inp2 = (const float*)d_in[1];
  const float* W1   = (const float*)d_in[2];
  const float* b1   = (const float*)d_in[3];
  const float* W2   = (const float*)d_in[4];
  const float* b2   = (const float*)d_in[5];
  float* out = (float*)d_out;

  char* ws = (char*)d_ws;
  unsigned short* wpt  = (unsigned short*)(ws + OFF_WPT);
  unsigned short* w2bt = (unsigned short*)(ws + OFF_W2BT);
  float* b1p = (float*)(ws + OFF_B1P);
  float* hf  = (float*)(ws + OFF_HF);
  unsigned short* hb = (unsigned short*)(ws + OFF_HB);

  k_repack<<<dim3(1032, 4), 256, 0, stream>>>(W1, wpt);
  k_misc<<<4096, 256, 0, stream>>>(W1, b1, W2, hf, w2bt, b1p);
  k_main<<<512, 512, 0, stream>>>(inp1, inp2, wpt, hf);
  k_finalize<<<4096, 256, 0, stream>>>(hf, b1p, hb);
  k_gemm2<<<dim3(32, 2), 256, 0, stream>>>(hb, w2bt, b2, out);
}